// Round 1
// baseline (515.086 us; speedup 1.0000x reference)
//
#include <hip/hip_runtime.h>

#define NCOLS 107

// CE over one categorical slice [S,E): data_true is exactly one-hot there, so
// logp[label] == dot(dec, true) over the slice. Full unroll keeps the slice in
// registers (max len 42), so max + sumexp need only one global read per elem.
template<int S, int E>
__device__ __forceinline__ float slice_ce(const float* __restrict__ dr,
                                          const float* __restrict__ tr) {
    constexpr int L = E - S;
    float v[L];
#pragma unroll
    for (int j = 0; j < L; ++j) v[j] = dr[S + j];
    float m = v[0];
#pragma unroll
    for (int j = 1; j < L; ++j) m = fmaxf(m, v[j]);
    float sum = 0.0f, dot = 0.0f;
#pragma unroll
    for (int j = 0; j < L; ++j) {
        sum += __expf(v[j] - m);
        dot = fmaf(v[j], tr[S + j], dot);
    }
    return m + __logf(sum) - dot;  // = -(x_label - logsumexp)
}

__global__ __launch_bounds__(256) void multiloss_main(
        const float* __restrict__ dec, const float* __restrict__ tru,
        float* __restrict__ ws, int nrows) {
    int row = blockIdx.x * blockDim.x + threadIdx.x;
    float mse = 0.0f, ce = 0.0f;
    if (row < nrows) {
        const float* dr = dec + (size_t)row * NCOLS;
        const float* tr = tru + (size_t)row * NCOLS;
        float d;
        d = dr[0]  - tr[0];  mse = fmaf(d, d, mse);
        d = dr[26] - tr[26]; mse = fmaf(d, d, mse);
        d = dr[62] - tr[62]; mse = fmaf(d, d, mse);
        d = dr[63] - tr[63]; mse = fmaf(d, d, mse);
        d = dr[64] - tr[64]; mse = fmaf(d, d, mse);
        ce += slice_ce<1, 10>(dr, tr);
        ce += slice_ce<10, 26>(dr, tr);
        ce += slice_ce<27, 34>(dr, tr);
        ce += slice_ce<34, 49>(dr, tr);
        ce += slice_ce<49, 55>(dr, tr);
        ce += slice_ce<55, 60>(dr, tr);
        ce += slice_ce<60, 62>(dr, tr);
        ce += slice_ce<65, 107>(dr, tr);
    }
    // wave (64-lane) shuffle reduction
#pragma unroll
    for (int off = 32; off > 0; off >>= 1) {
        mse += __shfl_down(mse, off, 64);
        ce  += __shfl_down(ce,  off, 64);
    }
    __shared__ float smse[4], sce[4];
    int wid  = threadIdx.x >> 6;
    int lane = threadIdx.x & 63;
    if (lane == 0) { smse[wid] = mse; sce[wid] = ce; }
    __syncthreads();
    if (threadIdx.x == 0) {
        float bm = smse[0] + smse[1] + smse[2] + smse[3];
        float bc = sce[0]  + sce[1]  + sce[2]  + sce[3];
        atomicAdd(&ws[0], bm);
        atomicAdd(&ws[1], bc);
    }
}

__global__ void multiloss_fin(const float* __restrict__ ws,
                              float* __restrict__ out, float invN) {
    float mse = ws[0] * invN;
    float ce  = ws[1] * invN;
    out[0] = mse + ce;  // multi_loss
    out[1] = mse;       // mse_loss
    out[2] = ce;        // ce_loss
}

extern "C" void kernel_launch(void* const* d_in, const int* in_sizes, int n_in,
                              void* d_out, int out_size, void* d_ws, size_t ws_size,
                              hipStream_t stream) {
    const float* dec = (const float*)d_in[0];
    const float* tru = (const float*)d_in[1];
    int nrows = in_sizes[0] / NCOLS;
    float* ws = (float*)d_ws;
    hipMemsetAsync(ws, 0, 2 * sizeof(float), stream);
    int blocks = (nrows + 255) / 256;
    multiloss_main<<<blocks, 256, 0, stream>>>(dec, tru, ws, nrows);
    multiloss_fin<<<1, 1, 0, stream>>>(ws, (float*)d_out, 1.0f / (float)nrows);
}

// Round 2
// 460.192 us; speedup vs baseline: 1.1193x; 1.1193x over previous
//
#include <hip/hip_runtime.h>

#define NCOLS 107
#define TROWS 64
#define TELEMS (TROWS * NCOLS)   // 6848 floats per array per tile
#define TVEC  (TELEMS / 4)       // 1712 float4s (tile byte size 27392 % 16 == 0)

// CE over slice [S,E): data_true is exactly one-hot there, so
// logp[label] == dot(dec, true) over the slice. dr/tr point into LDS.
template<int S, int E>
__device__ __forceinline__ float slice_ce_lds(const float* dr, const float* tr) {
    constexpr int L = E - S;
    float v[L];
#pragma unroll
    for (int j = 0; j < L; ++j) v[j] = dr[S + j];
    float m = v[0];
#pragma unroll
    for (int j = 1; j < L; ++j) m = fmaxf(m, v[j]);
    float sum = 0.0f, dot = 0.0f;
#pragma unroll
    for (int j = 0; j < L; ++j) {
        sum += __expf(v[j] - m);
        dot = fmaf(v[j], tr[S + j], dot);
    }
    return m + __logf(sum) - dot;
}

__global__ __launch_bounds__(256, 2) void multiloss_main(
        const float* __restrict__ dec, const float* __restrict__ tru,
        float2* __restrict__ ws, int nrows) {
    __shared__ float4 sdec4[TVEC];
    __shared__ float4 stru4[TVEC];
    const float* sdec = (const float*)sdec4;
    const float* stru = (const float*)stru4;

    int tile0 = blockIdx.x * TROWS;
    int rows_here = nrows - tile0;
    if (rows_here > TROWS) rows_here = TROWS;
    size_t base = (size_t)tile0 * NCOLS;

    if (rows_here == TROWS) {
        // fully coalesced: each wave-load covers 1 KB contiguous
        const float4* gd = (const float4*)(dec + base);
        const float4* gt = (const float4*)(tru + base);
        for (int i = threadIdx.x; i < TVEC; i += 256) {
            sdec4[i] = gd[i];
            stru4[i] = gt[i];
        }
    } else {  // partial tail tile (not hit for BATCH=524288, kept for safety)
        int n = rows_here * NCOLS;
        float* sd = (float*)sdec4;
        float* st = (float*)stru4;
        for (int i = threadIdx.x; i < n; i += 256) {
            sd[i] = dec[base + i];
            st[i] = tru[base + i];
        }
    }
    __syncthreads();

    // 4 threads per row; slices partitioned by cost (42 / 31 / 22 / ~17)
    int row  = threadIdx.x >> 2;
    int part = threadIdx.x & 3;
    float mse = 0.0f, ce = 0.0f;
    if (row < rows_here) {
        const float* dr = sdec + row * NCOLS;
        const float* tr = stru + row * NCOLS;
        if (part == 0) {
            ce += slice_ce_lds<65, 107>(dr, tr);
        } else if (part == 1) {
            ce += slice_ce_lds<10, 26>(dr, tr);
            ce += slice_ce_lds<34, 49>(dr, tr);
        } else if (part == 2) {
            ce += slice_ce_lds<1, 10>(dr, tr);
            ce += slice_ce_lds<27, 34>(dr, tr);
            ce += slice_ce_lds<49, 55>(dr, tr);
        } else {
            ce += slice_ce_lds<55, 60>(dr, tr);
            ce += slice_ce_lds<60, 62>(dr, tr);
            float d;
            d = dr[0]  - tr[0];  mse = fmaf(d, d, mse);
            d = dr[26] - tr[26]; mse = fmaf(d, d, mse);
            d = dr[62] - tr[62]; mse = fmaf(d, d, mse);
            d = dr[63] - tr[63]; mse = fmaf(d, d, mse);
            d = dr[64] - tr[64]; mse = fmaf(d, d, mse);
        }
    }

    // wave (64-lane) shuffle reduction, then cross-wave via LDS
#pragma unroll
    for (int off = 32; off > 0; off >>= 1) {
        mse += __shfl_down(mse, off, 64);
        ce  += __shfl_down(ce,  off, 64);
    }
    __shared__ float smse[4], sce[4];
    int wid  = threadIdx.x >> 6;
    int lane = threadIdx.x & 63;
    if (lane == 0) { smse[wid] = mse; sce[wid] = ce; }
    __syncthreads();
    if (threadIdx.x == 0) {
        float bm = smse[0] + smse[1] + smse[2] + smse[3];
        float bc = sce[0]  + sce[1]  + sce[2]  + sce[3];
        ws[blockIdx.x] = make_float2(bm, bc);  // distinct slot per block: no atomics, no memset
    }
}

__global__ __launch_bounds__(256) void multiloss_fin(
        const float2* __restrict__ ws, float* __restrict__ out,
        int nblocks, float invN) {
    float m = 0.0f, c = 0.0f;
    for (int i = threadIdx.x; i < nblocks; i += 256) {
        float2 v = ws[i];
        m += v.x; c += v.y;
    }
#pragma unroll
    for (int off = 32; off > 0; off >>= 1) {
        m += __shfl_down(m, off, 64);
        c += __shfl_down(c, off, 64);
    }
    __shared__ float sm[4], sc[4];
    int wid  = threadIdx.x >> 6;
    int lane = threadIdx.x & 63;
    if (lane == 0) { sm[wid] = m; sc[wid] = c; }
    __syncthreads();
    if (threadIdx.x == 0) {
        float mse = (sm[0] + sm[1] + sm[2] + sm[3]) * invN;
        float ce  = (sc[0] + sc[1] + sc[2] + sc[3]) * invN;
        out[0] = mse + ce;
        out[1] = mse;
        out[2] = ce;
    }
}

extern "C" void kernel_launch(void* const* d_in, const int* in_sizes, int n_in,
                              void* d_out, int out_size, void* d_ws, size_t ws_size,
                              hipStream_t stream) {
    const float* dec = (const float*)d_in[0];
    const float* tru = (const float*)d_in[1];
    int nrows = in_sizes[0] / NCOLS;
    int nblocks = (nrows + TROWS - 1) / TROWS;   // 8192 for BATCH=524288
    float2* ws = (float2*)d_ws;                  // needs nblocks*8 B = 64 KB
    multiloss_main<<<nblocks, 256, 0, stream>>>(dec, tru, ws, nrows);
    multiloss_fin<<<1, 256, 0, stream>>>(ws, (float*)d_out, nblocks,
                                         1.0f / (float)nrows);
}

// Round 3
// 449.274 us; speedup vs baseline: 1.1465x; 1.0243x over previous
//
#include <hip/hip_runtime.h>

#define NCOLS 107
#define TROWS 32
#define TFLOATS (TROWS * NCOLS)   // 3424 floats staged (dec only)
#define TVEC (TFLOATS / 4)        // 856 float4s (13696 B, 16B-aligned tiles)
#define THREADS 128
#define GRID 4096                 // 16384 tiles / 4096 blocks = 4 tiles each

// log-sum-exp over slice [S,E) of one row held in LDS.
// CE for the slice = lse - dot(dec,true); the dot part is accumulated
// linearly during staging (one-hot => logp[label] == dot over the slice).
template<int S, int E>
__device__ __forceinline__ float slice_lse(const float* dr) {
    constexpr int L = E - S;
    float v[L];
#pragma unroll
    for (int j = 0; j < L; ++j) v[j] = dr[S + j];
    float m = v[0];
#pragma unroll
    for (int j = 1; j < L; ++j) m = fmaxf(m, v[j]);
    float s = 0.0f;
#pragma unroll
    for (int j = 0; j < L; ++j) s += __expf(v[j] - m);
    return m + __logf(s);
}

__device__ __forceinline__ bool is_mse_col(int c) {
    // MSE cols {0,26,62,63,64}; every other col is in exactly one cat slice
    return (c == 0) | (c == 26) | ((unsigned)(c - 62) <= 2u);
}

__global__ __launch_bounds__(THREADS) void multiloss_main(
        const float* __restrict__ dec, const float* __restrict__ tru,
        float2* __restrict__ ws, int nrows, int ntiles) {
    __shared__ float4 sdec4[TVEC];
    float* sdec = (float*)sdec4;

    float mse = 0.0f, dot = 0.0f, lse = 0.0f;

    for (int tile = blockIdx.x; tile < ntiles; tile += GRID) {
        size_t base = (size_t)tile * TFLOATS;
        int rows_here = nrows - tile * TROWS;
        if (rows_here > TROWS) rows_here = TROWS;

        __syncthreads();  // prior iteration's LDS readers done before rewrite

        if (rows_here == TROWS) {
            const float4* gd = (const float4*)(dec + base);
            const float4* gt = (const float4*)(tru + base);
#pragma unroll
            for (int it = 0; it < 7; ++it) {
                int fi = it * THREADS + threadIdx.x;
                if (fi < TVEC) {
                    float4 dv = gd[fi];
                    float4 tv = gt[fi];
                    sdec4[fi] = dv;
                    int c0 = (fi * 4) % NCOLS;
                    float dk[4] = {dv.x, dv.y, dv.z, dv.w};
                    float tk[4] = {tv.x, tv.y, tv.z, tv.w};
#pragma unroll
                    for (int k = 0; k < 4; ++k) {
                        int c = c0 + k; if (c >= NCOLS) c -= NCOLS;
                        float d = dk[k], t = tk[k];
                        float df = d - t;
                        mse += is_mse_col(c) ? df * df : 0.0f;
                        dot += is_mse_col(c) ? 0.0f : d * t;
                    }
                }
            }
        } else {  // partial tail tile (not hit for BATCH=524288)
            int n = rows_here * NCOLS;
            for (int i = threadIdx.x; i < n; i += THREADS) {
                float d = dec[base + i], t = tru[base + i];
                sdec[i] = d;
                int c = i % NCOLS;
                float df = d - t;
                mse += is_mse_col(c) ? df * df : 0.0f;
                dot += is_mse_col(c) ? 0.0f : d * t;
            }
        }
        __syncthreads();

        // 4 threads per row compute the per-row lse terms from LDS
        int row  = threadIdx.x >> 2;
        int part = threadIdx.x & 3;
        if (row < rows_here) {
            const float* dr = sdec + row * NCOLS;
            if (part == 0) {
                lse += slice_lse<65, 107>(dr);
            } else if (part == 1) {
                lse += slice_lse<10, 26>(dr) + slice_lse<34, 49>(dr);
            } else if (part == 2) {
                lse += slice_lse<1, 10>(dr) + slice_lse<27, 34>(dr)
                     + slice_lse<49, 55>(dr);
            } else {
                lse += slice_lse<55, 60>(dr) + slice_lse<60, 62>(dr);
            }
        }
    }

    float ce = lse - dot;
    // wave (64-lane) shuffle reduction, then cross-wave via LDS
#pragma unroll
    for (int off = 32; off > 0; off >>= 1) {
        mse += __shfl_down(mse, off, 64);
        ce  += __shfl_down(ce,  off, 64);
    }
    __shared__ float sm[2], sc[2];
    int wid  = threadIdx.x >> 6;
    int lane = threadIdx.x & 63;
    if (lane == 0) { sm[wid] = mse; sc[wid] = ce; }
    __syncthreads();
    if (threadIdx.x == 0)
        ws[blockIdx.x] = make_float2(sm[0] + sm[1], sc[0] + sc[1]);
}

__global__ __launch_bounds__(256) void multiloss_fin(
        const float2* __restrict__ ws, float* __restrict__ out,
        int nblocks, float invN) {
    float m = 0.0f, c = 0.0f;
    for (int i = threadIdx.x; i < nblocks; i += 256) {
        float2 v = ws[i];
        m += v.x; c += v.y;
    }
#pragma unroll
    for (int off = 32; off > 0; off >>= 1) {
        m += __shfl_down(m, off, 64);
        c += __shfl_down(c, off, 64);
    }
    __shared__ float sm[4], sc[4];
    int wid  = threadIdx.x >> 6;
    int lane = threadIdx.x & 63;
    if (lane == 0) { sm[wid] = m; sc[wid] = c; }
    __syncthreads();
    if (threadIdx.x == 0) {
        float mse = (sm[0] + sm[1] + sm[2] + sm[3]) * invN;
        float ce  = (sc[0] + sc[1] + sc[2] + sc[3]) * invN;
        out[0] = mse + ce;
        out[1] = mse;
        out[2] = ce;
    }
}

extern "C" void kernel_launch(void* const* d_in, const int* in_sizes, int n_in,
                              void* d_out, int out_size, void* d_ws, size_t ws_size,
                              hipStream_t stream) {
    const float* dec = (const float*)d_in[0];
    const float* tru = (const float*)d_in[1];
    int nrows  = in_sizes[0] / NCOLS;
    int ntiles = (nrows + TROWS - 1) / TROWS;   // 16384
    float2* ws = (float2*)d_ws;                 // GRID*8 B = 32 KB
    multiloss_main<<<GRID, THREADS, 0, stream>>>(dec, tru, ws, nrows, ntiles);
    multiloss_fin<<<1, 256, 0, stream>>>(ws, (float*)d_out, GRID,
                                         1.0f / (float)nrows);
}